// Round 4
// baseline (601.885 us; speedup 1.0000x reference)
//
#include <hip/hip_runtime.h>
#include <hip/hip_bf16.h>

// Dims: B=256, Nv=196, Lt=32, Ci=768, Ct=512, H=12, D=64
// M1 = 50176 (=128*392), M2 = 8192 (=128*64), N = 768 (=128*6)

typedef __attribute__((ext_vector_type(8))) short bf16x8;
typedef __attribute__((ext_vector_type(4))) float f32x4;

__device__ __forceinline__ float bf2f(unsigned short u) {
    return __uint_as_float(((unsigned int)u) << 16);
}
__device__ __forceinline__ unsigned short f2bf(float f) {
    unsigned int x = __float_as_uint(f);
    unsigned int r = (x + 0x7FFFu + ((x >> 16) & 1u)) >> 16;  // RNE
    return (unsigned short)r;
}

// async global->LDS, 16B/lane. LDS dest is wave-uniform base + lane*16.
#define GLOAD_LDS16(gp, lp)                                                    \
    __builtin_amdgcn_global_load_lds(                                          \
        (__attribute__((address_space(1))) void*)(gp),                         \
        (__attribute__((address_space(3))) void*)(lp), 16, 0, 0)

// ---------------- fp32 -> bf16 convert (vectorized) ----------------
__global__ void cvt_bf16_kernel(const float* __restrict__ in,
                                unsigned short* __restrict__ out, int n4) {
    int i = blockIdx.x * 256 + threadIdx.x;
    if (i >= n4) return;
    float4 v = ((const float4*)in)[i];
    ushort4 o;
    o.x = f2bf(v.x); o.y = f2bf(v.y); o.z = f2bf(v.z); o.w = f2bf(v.w);
    ((ushort4*)out)[i] = o;
}

// ---------------- W[K][N] -> Wt[N][K] transpose + bf16 ----------------
__global__ void transpose_cvt_kernel(const float* __restrict__ W,
                                     unsigned short* __restrict__ Wt,
                                     int K, int N) {
    __shared__ float tile[32][33];
    int n0 = blockIdx.x * 32, k0 = blockIdx.y * 32;
    int tx = threadIdx.x & 31, ty = threadIdx.x >> 5;  // 256 thr: ty 0..7
    #pragma unroll
    for (int r = ty; r < 32; r += 8)
        tile[r][tx] = W[(size_t)(k0 + r) * N + n0 + tx];
    __syncthreads();
    #pragma unroll
    for (int r = ty; r < 32; r += 8)
        Wt[(size_t)(n0 + r) * K + k0 + tx] = f2bf(tile[tx][r]);
}

// ---------------- bf16 MFMA GEMM (m97 structure): C = A * Bt^T + bias -------
// 128x128 tile, BK=64, 4 waves 2x2, global_load_lds width=16 staging.
// LDS image per 8-row group is CHUNK-MAJOR [c8][row] (staging lane: row=lane&7,
// chunk=lane>>3) so fragment ds_read_b128 hits rows at 16B stride -> all 32
// banks once per 8 lanes, 2-way max across half-groups (free per m136).
// XCD swizzle: xcd=id&7 owns a contiguous 1/8 of m-tiles -> A-stripe stays in
// one XCD's L2.
template<int KTOT, int GELU, int MTILES>
__global__ __launch_bounds__(256, 2)
void gemm_bt_kernel(const unsigned short* __restrict__ A,
                    const unsigned short* __restrict__ Bt,
                    const float* __restrict__ bias,
                    unsigned short* __restrict__ C) {
    constexpr int GS = 520;  // 8-row group stride in shorts (512 + 8 pad)
    __shared__ unsigned short As[16 * GS];
    __shared__ unsigned short Bs[16 * GS];
    const int tid = threadIdx.x;
    const int lane = tid & 63, wave = tid >> 6;
    const int id = blockIdx.x;
    const int xcd = id & 7, local = id >> 3;
    const int nt = local % 6, mt = xcd * (MTILES / 8) + local / 6;
    const size_t m0 = (size_t)mt * 128;
    const int n0 = nt * 128;
    const int wm = (wave >> 1) * 64, wn = (wave & 1) * 64;
    const int lr = lane & 15, quad = lane >> 4;

    // staging: wave stages groups [wave*4, wave*4+4), 8 rows/instr.
    // lane -> row wave*32 + i*8 + (lane&7), col chunk (lane>>3)*8
    const unsigned short* gA = A + (m0 + wave * 32 + (lane & 7)) * KTOT + (lane >> 3) * 8;
    const unsigned short* gB = Bt + ((size_t)n0 + wave * 32 + (lane & 7)) * KTOT + (lane >> 3) * 8;
    unsigned short* lA = As + (wave * 4) * GS;
    unsigned short* lB = Bs + (wave * 4) * GS;

    f32x4 acc[4][4] = {};

    for (int kt = 0; kt < KTOT; kt += 64) {
        #pragma unroll
        for (int i = 0; i < 4; ++i) {
            GLOAD_LDS16(gA + (size_t)i * 8 * KTOT + kt, lA + i * GS);
            GLOAD_LDS16(gB + (size_t)i * 8 * KTOT + kt, lB + i * GS);
        }
        __syncthreads();  // compiler drains vmcnt(0) before barrier
        #pragma unroll
        for (int kk = 0; kk < 64; kk += 32) {
            bf16x8 fa[4], fb[4];
            #pragma unroll
            for (int i = 0; i < 4; ++i) {
                int r = wm + i * 16 + lr;
                fa[i] = *(const bf16x8*)(As + (r >> 3) * GS + ((kk >> 3) + quad) * 64 + (r & 7) * 8);
            }
            #pragma unroll
            for (int j = 0; j < 4; ++j) {
                int r = wn + j * 16 + lr;
                fb[j] = *(const bf16x8*)(Bs + (r >> 3) * GS + ((kk >> 3) + quad) * 64 + (r & 7) * 8);
            }
            #pragma unroll
            for (int i = 0; i < 4; ++i)
                #pragma unroll
                for (int j = 0; j < 4; ++j)
                    acc[i][j] = __builtin_amdgcn_mfma_f32_16x16x32_bf16(
                        fa[i], fb[j], acc[i][j], 0, 0, 0);
        }
        __syncthreads();
    }

    // epilogue: C/D layout col=lane&15, row=quad*4+reg  [m89-verified]
    #pragma unroll
    for (int j = 0; j < 4; ++j) {
        int col = n0 + wn + j * 16 + lr;
        float bv = bias[col];
        #pragma unroll
        for (int i = 0; i < 4; ++i) {
            #pragma unroll
            for (int r = 0; r < 4; ++r) {
                size_t row = m0 + wm + i * 16 + quad * 4 + r;
                float x = acc[i][j][r] + bv;
                if (GELU) x = x / (1.0f + __expf(-1.702f * x));  // quick_gelu
                C[row * 768 + col] = f2bf(x);
            }
        }
    }
}

// ---------------- MFMA attention: one block per (b,h), 4 waves -------------
__global__ __launch_bounds__(256, 4)
void attn_mfma_kernel(const unsigned short* __restrict__ Q,
                      const unsigned short* __restrict__ Kb,
                      const unsigned short* __restrict__ Vb,
                      unsigned short* __restrict__ RF) {
    constexpr int KS = 72;  // Ks row stride
    constexpr int VS = 34;  // Vt row stride
    constexpr int PS = 40;  // P row stride
    constexpr int CS = 72;  // ctx row stride
    __shared__ unsigned short Ks[32 * KS];      // K rows  [l][d]
    __shared__ unsigned short Vt[64 * VS];      // V^T     [d][l]
    __shared__ unsigned short Pb[4][16 * PS];   // per-wave P  [m][l]
    __shared__ unsigned short Cb[4][16 * CS];   // per-wave ctx[m][d]
    const int tid = threadIdx.x;
    const int b = blockIdx.x / 12, h = blockIdx.x % 12;
    const int lane = tid & 63, wave = tid >> 6;
    const int lr = lane & 15, quad = lane >> 4;

    {   // stage K rows + V transposed (bf16, one-time)
        int l = tid >> 3, d8 = (tid & 7) * 8;
        size_t base = ((size_t)b * 32 + l) * 768 + (size_t)h * 64 + d8;
        bf16x8 kv = *(const bf16x8*)(Kb + base);
        bf16x8 vv = *(const bf16x8*)(Vb + base);
        *(bf16x8*)(Ks + l * KS + d8) = kv;
        #pragma unroll
        for (int j = 0; j < 8; ++j)
            Vt[(d8 + j) * VS + l] = (unsigned short)vv[j];
    }
    __syncthreads();

    bf16x8 fbK[2][2];
    #pragma unroll
    for (int n = 0; n < 2; ++n)
        #pragma unroll
        for (int ks = 0; ks < 2; ++ks)
            fbK[n][ks] = *(const bf16x8*)(Ks + (n * 16 + lr) * KS + ks * 32 + quad * 8);
    bf16x8 fbV[4];
    #pragma unroll
    for (int d = 0; d < 4; ++d)
        fbV[d] = *(const bf16x8*)(Vt + (d * 16 + lr) * VS + quad * 8);

    const size_t qbase = (size_t)b * 196 * 768 + (size_t)h * 64;

    for (int t = wave; t < 13; t += 4) {   // 13 tiles of 16 rows cover 196
        const int m0 = t * 16;
        int qrow = m0 + lr; if (qrow > 195) qrow = 195;  // clamp tail dups
        const unsigned short* qp = Q + qbase + (size_t)qrow * 768;
        bf16x8 fa0 = *(const bf16x8*)(qp + quad * 8);
        bf16x8 fa1 = *(const bf16x8*)(qp + 32 + quad * 8);
        f32x4 s0 = {}, s1 = {};
        s0 = __builtin_amdgcn_mfma_f32_16x16x32_bf16(fa0, fbK[0][0], s0, 0, 0, 0);
        s0 = __builtin_amdgcn_mfma_f32_16x16x32_bf16(fa1, fbK[0][1], s0, 0, 0, 0);
        s1 = __builtin_amdgcn_mfma_f32_16x16x32_bf16(fa0, fbK[1][0], s1, 0, 0, 0);
        s1 = __builtin_amdgcn_mfma_f32_16x16x32_bf16(fa1, fbK[1][1], s1, 0, 0, 0);

        float p0[4], p1[4], m4[4], s4[4];
        #pragma unroll
        for (int r = 0; r < 4; ++r) {
            p0[r] = s0[r] * 0.125f;
            p1[r] = s1[r] * 0.125f;
            m4[r] = fmaxf(p0[r], p1[r]);
        }
        #pragma unroll
        for (int off = 1; off < 16; off <<= 1)
            #pragma unroll
            for (int r = 0; r < 4; ++r)
                m4[r] = fmaxf(m4[r], __shfl_xor(m4[r], off));
        #pragma unroll
        for (int r = 0; r < 4; ++r) {
            p0[r] = __expf(p0[r] - m4[r]);
            p1[r] = __expf(p1[r] - m4[r]);
            s4[r] = p0[r] + p1[r];
        }
        #pragma unroll
        for (int off = 1; off < 16; off <<= 1)
            #pragma unroll
            for (int r = 0; r < 4; ++r)
                s4[r] += __shfl_xor(s4[r], off);
        #pragma unroll
        for (int r = 0; r < 4; ++r) {
            float inv = __builtin_amdgcn_rcpf(s4[r]);
            unsigned short* pr = &Pb[wave][(quad * 4 + r) * PS];
            pr[lr]      = f2bf(p0[r] * inv);
            pr[16 + lr] = f2bf(p1[r] * inv);
        }

        bf16x8 fap = *(const bf16x8*)(&Pb[wave][lr * PS + quad * 8]);
        f32x4 c[4];
        #pragma unroll
        for (int d = 0; d < 4; ++d) {
            f32x4 z = {};
            c[d] = __builtin_amdgcn_mfma_f32_16x16x32_bf16(fap, fbV[d], z, 0, 0, 0);
        }
        #pragma unroll
        for (int d = 0; d < 4; ++d)
            #pragma unroll
            for (int r = 0; r < 4; ++r)
                Cb[wave][(quad * 4 + r) * CS + d * 16 + lr] = f2bf(c[d][r]);
        #pragma unroll
        for (int i = 0; i < 2; ++i) {
            int c2 = lane + i * 64;
            int row = c2 >> 3, col8 = (c2 & 7) * 8;
            int grow = m0 + row;
            if (grow < 196) {
                bf16x8 cv = *(const bf16x8*)(&Cb[wave][row * CS + col8]);
                unsigned short* gp = RF + qbase + (size_t)grow * 768 + col8;
                bf16x8 rv = *(const bf16x8*)gp;
                bf16x8 ov;
                #pragma unroll
                for (int j = 0; j < 8; ++j)
                    ov[j] = (short)f2bf(bf2f((unsigned short)cv[j]) +
                                        bf2f((unsigned short)rv[j]));
                *(bf16x8*)gp = ov;
            }
        }
    }
}

// ---------------- MLP2: logits[m][0..1] = h[m] . W2 + b2 ; rel fill --------
__global__ __launch_bounds__(256)
void mlp2_kernel(const unsigned short* __restrict__ Hb,
                 const float* __restrict__ W2,   // [768][2]
                 const float* __restrict__ b2,
                 float* __restrict__ out) {
    __shared__ float w2s[2][768];
    const int tid = threadIdx.x;
    for (int i = tid; i < 1536; i += 256) w2s[i & 1][i >> 1] = W2[i];
    __syncthreads();
    const int sub = tid & 7;
    const int r = tid >> 3;                       // 0..31 rows per block
    const size_t row = (size_t)blockIdx.x * 32 + r;
    float a0 = 0.f, a1 = 0.f;
    #pragma unroll
    for (int i = 0; i < 12; ++i) {
        int base = i * 64 + sub * 8;
        bf16x8 hv = *(const bf16x8*)(Hb + row * 768 + base);
        #pragma unroll
        for (int j = 0; j < 8; ++j) {
            float hf = bf2f((unsigned short)hv[j]);
            a0 += hf * w2s[0][base + j];
            a1 += hf * w2s[1][base + j];
        }
    }
    #pragma unroll
    for (int o = 4; o >= 1; o >>= 1) {
        a0 += __shfl_down(a0, o, 8);
        a1 += __shfl_down(a1, o, 8);
    }
    if (sub == 0) {
        out[row * 2]      = a0 + b2[0];
        out[row * 2 + 1]  = a1 + b2[1];
        // rel_BN: softmax rows sum to 1 -> mean over Lt = 1/32, mean over H = 1/32
        out[100352 + row] = 0.03125f;
    }
}

extern "C" void kernel_launch(void* const* d_in, const int* in_sizes, int n_in,
                              void* d_out, int out_size, void* d_ws, size_t ws_size,
                              hipStream_t stream) {
    const float* vis = (const float*)d_in[0];
    const float* txt = (const float*)d_in[1];
    const float* Wq  = (const float*)d_in[2];
    const float* bq  = (const float*)d_in[3];
    const float* Wk  = (const float*)d_in[4];
    const float* bk  = (const float*)d_in[5];
    const float* Wv  = (const float*)d_in[6];
    const float* bv  = (const float*)d_in[7];
    const float* W1  = (const float*)d_in[8];
    const float* b1  = (const float*)d_in[9];
    const float* W2  = (const float*)d_in[10];
    const float* b2  = (const float*)d_in[11];
    float* out = (float*)d_out;

    char* w = (char*)d_ws;
    unsigned short* Abf = (unsigned short*)(w);              // 77,070,336 B (vis bf16; becomes "fused")
    unsigned short* Tbf = (unsigned short*)(w + 77070336);   //  8,388,608 B (text bf16)
    unsigned short* Wqt = (unsigned short*)(w + 85458944);   //  1,179,648 B
    unsigned short* Wkt = (unsigned short*)(w + 86638592);   //    786,432 B
    unsigned short* Wvt = (unsigned short*)(w + 87425024);   //    786,432 B
    unsigned short* W1t = (unsigned short*)(w + 88211456);   //  1,179,648 B
    unsigned short* Qbf = (unsigned short*)(w + 89391104);   // 77,070,336 B (Q; reused as H after attn)
    unsigned short* Kbf = (unsigned short*)(w + 166461440);  // 12,582,912 B
    unsigned short* Vbf = (unsigned short*)(w + 179044352);  // 12,582,912 B
    unsigned short* Hbf = Qbf;  // Q dead after attention

    cvt_bf16_kernel<<<37632, 256, 0, stream>>>(vis, Abf, 9633792);
    cvt_bf16_kernel<<<4096, 256, 0, stream>>>(txt, Tbf, 1048576);
    transpose_cvt_kernel<<<dim3(24, 24), 256, 0, stream>>>(Wq, Wqt, 768, 768);
    transpose_cvt_kernel<<<dim3(24, 16), 256, 0, stream>>>(Wk, Wkt, 512, 768);
    transpose_cvt_kernel<<<dim3(24, 16), 256, 0, stream>>>(Wv, Wvt, 512, 768);
    transpose_cvt_kernel<<<dim3(24, 24), 256, 0, stream>>>(W1, W1t, 768, 768);

    gemm_bt_kernel<768, 0, 392><<<2352, 256, 0, stream>>>(Abf, Wqt, bq, Qbf);
    gemm_bt_kernel<512, 0, 64><<<384, 256, 0, stream>>>(Tbf, Wkt, bk, Kbf);
    gemm_bt_kernel<512, 0, 64><<<384, 256, 0, stream>>>(Tbf, Wvt, bv, Vbf);

    attn_mfma_kernel<<<3072, 256, 0, stream>>>(Qbf, Kbf, Vbf, Abf);

    gemm_bt_kernel<768, 1, 392><<<2352, 256, 0, stream>>>(Abf, W1t, b1, Hbf);

    mlp2_kernel<<<1568, 256, 0, stream>>>(Hbf, W2, b2, out);
}

// Round 5
// 508.840 us; speedup vs baseline: 1.1829x; 1.1829x over previous
//
#include <hip/hip_runtime.h>
#include <hip/hip_bf16.h>

// Dims: B=256, Nv=196, Lt=32, Ci=768, Ct=512, H=12, D=64
// M1 = 50176 (=128*392), M2 = 8192 (=128*64), N = 768 (=128*6)

typedef __attribute__((ext_vector_type(8))) short bf16x8;
typedef __attribute__((ext_vector_type(4))) float f32x4;

__device__ __forceinline__ float bf2f(unsigned short u) {
    return __uint_as_float(((unsigned int)u) << 16);
}
__device__ __forceinline__ unsigned short f2bf(float f) {
    unsigned int x = __float_as_uint(f);
    unsigned int r = (x + 0x7FFFu + ((x >> 16) & 1u)) >> 16;  // RNE
    return (unsigned short)r;
}

// async global->LDS, 16B/lane. LDS dest is wave-uniform base + lane*16.
#define GLOAD_LDS16(gp, lp)                                                    \
    __builtin_amdgcn_global_load_lds(                                          \
        (__attribute__((address_space(1))) void*)(gp),                         \
        (__attribute__((address_space(3))) void*)(lp), 16, 0, 0)

// ---------------- fp32 -> bf16 convert (vectorized) ----------------
__global__ void cvt_bf16_kernel(const float* __restrict__ in,
                                unsigned short* __restrict__ out, int n4) {
    int i = blockIdx.x * 256 + threadIdx.x;
    if (i >= n4) return;
    float4 v = ((const float4*)in)[i];
    ushort4 o;
    o.x = f2bf(v.x); o.y = f2bf(v.y); o.z = f2bf(v.z); o.w = f2bf(v.w);
    ((ushort4*)out)[i] = o;
}

// ---------------- W[K][N] -> Wt[N][K] transpose + bf16 ----------------
__global__ void transpose_cvt_kernel(const float* __restrict__ W,
                                     unsigned short* __restrict__ Wt,
                                     int K, int N) {
    __shared__ float tile[32][33];
    int n0 = blockIdx.x * 32, k0 = blockIdx.y * 32;
    int tx = threadIdx.x & 31, ty = threadIdx.x >> 5;  // 256 thr: ty 0..7
    #pragma unroll
    for (int r = ty; r < 32; r += 8)
        tile[r][tx] = W[(size_t)(k0 + r) * N + n0 + tx];
    __syncthreads();
    #pragma unroll
    for (int r = ty; r < 32; r += 8)
        Wt[(size_t)(n0 + r) * K + k0 + tx] = f2bf(tile[tx][r]);
}

// ---------------- bf16 MFMA GEMM (m97 structure): C = A * Bt^T + bias -------
// 128x128 tile, BK=64, 4 waves 2x2, global_load_lds width=16 staging.
// Staging keeps r3's coalesced mapping (lane: row=lane>>3, 8 lanes = one row's
// contiguous 128B) but each lane fetches global chunk (lane&7)^(lane>>3) of
// its row (permutation WITHIN the 128B segment -> same cache lines). The LDS
// image thus holds row r's chunk g at slot g^(r&7): a fragment ds_read_b128
// (fixed g, rows varying) hits banks 4*(g^(r&7)) -> all 32 banks once per 8
// rows, 2-way across half-groups (free, m136). XCD swizzle: xcd=id&7 owns a
// contiguous 1/8 of m-tiles -> A-stripe stays in one XCD's L2.
template<int KTOT, int GELU, int MTILES>
__global__ __launch_bounds__(256, 2)
void gemm_bt_kernel(const unsigned short* __restrict__ A,
                    const unsigned short* __restrict__ Bt,
                    const float* __restrict__ bias,
                    unsigned short* __restrict__ C) {
    constexpr int GS = 520;  // 8-row group stride in shorts (512 + 8 pad)
    __shared__ unsigned short As[16 * GS];
    __shared__ unsigned short Bs[16 * GS];
    const int tid = threadIdx.x;
    const int lane = tid & 63, wave = tid >> 6;
    const int id = blockIdx.x;
    const int xcd = id & 7, local = id >> 3;
    const int nt = local % 6, mt = xcd * (MTILES / 8) + local / 6;
    const size_t m0 = (size_t)mt * 128;
    const int n0 = nt * 128;
    const int wm = (wave >> 1) * 64, wn = (wave & 1) * 64;
    const int lr = lane & 15, quad = lane >> 4;

    // staging: wave stages groups [wave*4, wave*4+4), 8 rows/instr.
    // lane -> row wave*32 + i*8 + (lane>>3), col chunk ((lane&7)^(lane>>3))*8
    const int swz = ((lane & 7) ^ (lane >> 3)) * 8;
    const unsigned short* gA = A + (m0 + wave * 32 + (lane >> 3)) * KTOT + swz;
    const unsigned short* gB = Bt + ((size_t)n0 + wave * 32 + (lane >> 3)) * KTOT + swz;
    unsigned short* lA = As + (wave * 4) * GS;
    unsigned short* lB = Bs + (wave * 4) * GS;

    f32x4 acc[4][4] = {};

    for (int kt = 0; kt < KTOT; kt += 64) {
        #pragma unroll
        for (int i = 0; i < 4; ++i) {
            GLOAD_LDS16(gA + (size_t)i * 8 * KTOT + kt, lA + i * GS);
            GLOAD_LDS16(gB + (size_t)i * 8 * KTOT + kt, lB + i * GS);
        }
        __syncthreads();  // compiler drains vmcnt(0) before barrier
        #pragma unroll
        for (int kk = 0; kk < 64; kk += 32) {
            bf16x8 fa[4], fb[4];
            #pragma unroll
            for (int i = 0; i < 4; ++i) {
                int r = wm + i * 16 + lr;
                int g = (kk >> 3) + quad;             // global chunk index
                fa[i] = *(const bf16x8*)(As + (r >> 3) * GS + (r & 7) * 64 +
                                         ((g ^ (r & 7)) << 3));
            }
            #pragma unroll
            for (int j = 0; j < 4; ++j) {
                int r = wn + j * 16 + lr;
                int g = (kk >> 3) + quad;
                fb[j] = *(const bf16x8*)(Bs + (r >> 3) * GS + (r & 7) * 64 +
                                         ((g ^ (r & 7)) << 3));
            }
            #pragma unroll
            for (int i = 0; i < 4; ++i)
                #pragma unroll
                for (int j = 0; j < 4; ++j)
                    acc[i][j] = __builtin_amdgcn_mfma_f32_16x16x32_bf16(
                        fa[i], fb[j], acc[i][j], 0, 0, 0);
        }
        __syncthreads();
    }

    // epilogue: C/D layout col=lane&15, row=quad*4+reg  [m89-verified]
    #pragma unroll
    for (int j = 0; j < 4; ++j) {
        int col = n0 + wn + j * 16 + lr;
        float bv = bias[col];
        #pragma unroll
        for (int i = 0; i < 4; ++i) {
            #pragma unroll
            for (int r = 0; r < 4; ++r) {
                size_t row = m0 + wm + i * 16 + quad * 4 + r;
                float x = acc[i][j][r] + bv;
                if (GELU) x = x / (1.0f + __expf(-1.702f * x));  // quick_gelu
                C[row * 768 + col] = f2bf(x);
            }
        }
    }
}

// ---------------- MFMA attention: one block per (b,h), 4 waves -------------
__global__ __launch_bounds__(256, 4)
void attn_mfma_kernel(const unsigned short* __restrict__ Q,
                      const unsigned short* __restrict__ Kb,
                      const unsigned short* __restrict__ Vb,
                      unsigned short* __restrict__ RF) {
    constexpr int KS = 72;  // Ks row stride
    constexpr int VS = 34;  // Vt row stride
    constexpr int PS = 40;  // P row stride
    constexpr int CS = 72;  // ctx row stride
    __shared__ unsigned short Ks[32 * KS];      // K rows  [l][d]
    __shared__ unsigned short Vt[64 * VS];      // V^T     [d][l]
    __shared__ unsigned short Pb[4][16 * PS];   // per-wave P  [m][l]
    __shared__ unsigned short Cb[4][16 * CS];   // per-wave ctx[m][d]
    const int tid = threadIdx.x;
    const int b = blockIdx.x / 12, h = blockIdx.x % 12;
    const int lane = tid & 63, wave = tid >> 6;
    const int lr = lane & 15, quad = lane >> 4;

    {   // stage K rows + V transposed (bf16, one-time)
        int l = tid >> 3, d8 = (tid & 7) * 8;
        size_t base = ((size_t)b * 32 + l) * 768 + (size_t)h * 64 + d8;
        bf16x8 kv = *(const bf16x8*)(Kb + base);
        bf16x8 vv = *(const bf16x8*)(Vb + base);
        *(bf16x8*)(Ks + l * KS + d8) = kv;
        #pragma unroll
        for (int j = 0; j < 8; ++j)
            Vt[(d8 + j) * VS + l] = (unsigned short)vv[j];
    }
    __syncthreads();

    bf16x8 fbK[2][2];
    #pragma unroll
    for (int n = 0; n < 2; ++n)
        #pragma unroll
        for (int ks = 0; ks < 2; ++ks)
            fbK[n][ks] = *(const bf16x8*)(Ks + (n * 16 + lr) * KS + ks * 32 + quad * 8);
    bf16x8 fbV[4];
    #pragma unroll
    for (int d = 0; d < 4; ++d)
        fbV[d] = *(const bf16x8*)(Vt + (d * 16 + lr) * VS + quad * 8);

    const size_t qbase = (size_t)b * 196 * 768 + (size_t)h * 64;

    for (int t = wave; t < 13; t += 4) {   // 13 tiles of 16 rows cover 196
        const int m0 = t * 16;
        int qrow = m0 + lr; if (qrow > 195) qrow = 195;  // clamp tail dups
        const unsigned short* qp = Q + qbase + (size_t)qrow * 768;
        bf16x8 fa0 = *(const bf16x8*)(qp + quad * 8);
        bf16x8 fa1 = *(const bf16x8*)(qp + 32 + quad * 8);
        f32x4 s0 = {}, s1 = {};
        s0 = __builtin_amdgcn_mfma_f32_16x16x32_bf16(fa0, fbK[0][0], s0, 0, 0, 0);
        s0 = __builtin_amdgcn_mfma_f32_16x16x32_bf16(fa1, fbK[0][1], s0, 0, 0, 0);
        s1 = __builtin_amdgcn_mfma_f32_16x16x32_bf16(fa0, fbK[1][0], s1, 0, 0, 0);
        s1 = __builtin_amdgcn_mfma_f32_16x16x32_bf16(fa1, fbK[1][1], s1, 0, 0, 0);

        float p0[4], p1[4], m4[4], s4[4];
        #pragma unroll
        for (int r = 0; r < 4; ++r) {
            p0[r] = s0[r] * 0.125f;
            p1[r] = s1[r] * 0.125f;
            m4[r] = fmaxf(p0[r], p1[r]);
        }
        #pragma unroll
        for (int off = 1; off < 16; off <<= 1)
            #pragma unroll
            for (int r = 0; r < 4; ++r)
                m4[r] = fmaxf(m4[r], __shfl_xor(m4[r], off));
        #pragma unroll
        for (int r = 0; r < 4; ++r) {
            p0[r] = __expf(p0[r] - m4[r]);
            p1[r] = __expf(p1[r] - m4[r]);
            s4[r] = p0[r] + p1[r];
        }
        #pragma unroll
        for (int off = 1; off < 16; off <<= 1)
            #pragma unroll
            for (int r = 0; r < 4; ++r)
                s4[r] += __shfl_xor(s4[r], off);
        #pragma unroll
        for (int r = 0; r < 4; ++r) {
            float inv = __builtin_amdgcn_rcpf(s4[r]);
            unsigned short* pr = &Pb[wave][(quad * 4 + r) * PS];
            pr[lr]      = f2bf(p0[r] * inv);
            pr[16 + lr] = f2bf(p1[r] * inv);
        }

        bf16x8 fap = *(const bf16x8*)(&Pb[wave][lr * PS + quad * 8]);
        f32x4 c[4];
        #pragma unroll
        for (int d = 0; d < 4; ++d) {
            f32x4 z = {};
            c[d] = __builtin_amdgcn_mfma_f32_16x16x32_bf16(fap, fbV[d], z, 0, 0, 0);
        }
        #pragma unroll
        for (int d = 0; d < 4; ++d)
            #pragma unroll
            for (int r = 0; r < 4; ++r)
                Cb[wave][(quad * 4 + r) * CS + d * 16 + lr] = f2bf(c[d][r]);
        #pragma unroll
        for (int i = 0; i < 2; ++i) {
            int c2 = lane + i * 64;
            int row = c2 >> 3, col8 = (c2 & 7) * 8;
            int grow = m0 + row;
            if (grow < 196) {
                bf16x8 cv = *(const bf16x8*)(&Cb[wave][row * CS + col8]);
                unsigned short* gp = RF + qbase + (size_t)grow * 768 + col8;
                bf16x8 rv = *(const bf16x8*)gp;
                bf16x8 ov;
                #pragma unroll
                for (int j = 0; j < 8; ++j)
                    ov[j] = (short)f2bf(bf2f((unsigned short)cv[j]) +
                                        bf2f((unsigned short)rv[j]));
                *(bf16x8*)gp = ov;
            }
        }
    }
}

// ---------------- MLP2: logits[m][0..1] = h[m] . W2 + b2 ; rel fill --------
__global__ __launch_bounds__(256)
void mlp2_kernel(const unsigned short* __restrict__ Hb,
                 const float* __restrict__ W2,   // [768][2]
                 const float* __restrict__ b2,
                 float* __restrict__ out) {
    __shared__ float w2s[2][768];
    const int tid = threadIdx.x;
    for (int i = tid; i < 1536; i += 256) w2s[i & 1][i >> 1] = W2[i];
    __syncthreads();
    const int sub = tid & 7;
    const int r = tid >> 3;                       // 0..31 rows per block
    const size_t row = (size_t)blockIdx.x * 32 + r;
    float a0 = 0.f, a1 = 0.f;
    #pragma unroll
    for (int i = 0; i < 12; ++i) {
        int base = i * 64 + sub * 8;
        bf16x8 hv = *(const bf16x8*)(Hb + row * 768 + base);
        #pragma unroll
        for (int j = 0; j < 8; ++j) {
            float hf = bf2f((unsigned short)hv[j]);
            a0 += hf * w2s[0][base + j];
            a1 += hf * w2s[1][base + j];
        }
    }
    #pragma unroll
    for (int o = 4; o >= 1; o >>= 1) {
        a0 += __shfl_down(a0, o, 8);
        a1 += __shfl_down(a1, o, 8);
    }
    if (sub == 0) {
        out[row * 2]      = a0 + b2[0];
        out[row * 2 + 1]  = a1 + b2[1];
        // rel_BN: softmax rows sum to 1 -> mean over Lt = 1/32, mean over H = 1/32
        out[100352 + row] = 0.03125f;
    }
}

extern "C" void kernel_launch(void* const* d_in, const int* in_sizes, int n_in,
                              void* d_out, int out_size, void* d_ws, size_t ws_size,
                              hipStream_t stream) {
    const float* vis = (const float*)d_in[0];
    const float* txt = (const float*)d_in[1];
    const float* Wq  = (const float*)d_in[2];
    const float* bq  = (const float*)d_in[3];
    const float* Wk  = (const float*)d_in[4];
    const float* bk  = (const float*)d_in[5];
    const float* Wv  = (const float*)d_in[6];
    const float* bv  = (const float*)d_in[7];
    const float* W1  = (const float*)d_in[8];
    const float* b1  = (const float*)d_in[9];
    const float* W2  = (const float*)d_in[10];
    const float* b2  = (const float*)d_in[11];
    float* out = (float*)d_out;

    char* w = (char*)d_ws;
    unsigned short* Abf = (unsigned short*)(w);              // 77,070,336 B (vis bf16; becomes "fused")
    unsigned short* Tbf = (unsigned short*)(w + 77070336);   //  8,388,608 B (text bf16)
    unsigned short* Wqt = (unsigned short*)(w + 85458944);   //  1,179,648 B
    unsigned short* Wkt = (unsigned short*)(w + 86638592);   //    786,432 B
    unsigned short* Wvt = (unsigned short*)(w + 87425024);   //    786,432 B
    unsigned short* W1t = (unsigned short*)(w + 88211456);   //  1,179,648 B
    unsigned short* Qbf = (unsigned short*)(w + 89391104);   // 77,070,336 B (Q; reused as H after attn)
    unsigned short* Kbf = (unsigned short*)(w + 166461440);  // 12,582,912 B
    unsigned short* Vbf = (unsigned short*)(w + 179044352);  // 12,582,912 B
    unsigned short* Hbf = Qbf;  // Q dead after attention

    cvt_bf16_kernel<<<37632, 256, 0, stream>>>(vis, Abf, 9633792);
    cvt_bf16_kernel<<<4096, 256, 0, stream>>>(txt, Tbf, 1048576);
    transpose_cvt_kernel<<<dim3(24, 24), 256, 0, stream>>>(Wq, Wqt, 768, 768);
    transpose_cvt_kernel<<<dim3(24, 16), 256, 0, stream>>>(Wk, Wkt, 512, 768);
    transpose_cvt_kernel<<<dim3(24, 16), 256, 0, stream>>>(Wv, Wvt, 512, 768);
    transpose_cvt_kernel<<<dim3(24, 24), 256, 0, stream>>>(W1, W1t, 768, 768);

    gemm_bt_kernel<768, 0, 392><<<2352, 256, 0, stream>>>(Abf, Wqt, bq, Qbf);
    gemm_bt_kernel<512, 0, 64><<<384, 256, 0, stream>>>(Tbf, Wkt, bk, Kbf);
    gemm_bt_kernel<512, 0, 64><<<384, 256, 0, stream>>>(Tbf, Wvt, bv, Vbf);

    attn_mfma_kernel<<<3072, 256, 0, stream>>>(Qbf, Kbf, Vbf, Abf);

    gemm_bt_kernel<768, 1, 392><<<2352, 256, 0, stream>>>(Abf, W1t, b1, Hbf);

    mlp2_kernel<<<1568, 256, 0, stream>>>(Hbf, W2, b2, out);
}